// Round 1
// baseline (1243.109 us; speedup 1.0000x reference)
//
#include <hip/hip_runtime.h>

// SRLoss: loss = mean((inp - avgpool10x10(output))^2) + BCE(output, target)
// output/target: [32,1,1280,1280] f32; inp: [32,1,128,128] f32; out: scalar f32.
//
// R5: counters showed latency/occupancy-bound (VALUBusy 13%, HBM 19%, Occ 30%,
// effective 3.05 TB/s vs 6.3 achievable). 4096 short blocks churned launch /
// teardown. Now: 4 bands per block -> grid 1024 = exactly 4 blocks/CU fully
// resident; one continuous PD=5 rotating float4 pipeline across all 40 row
// iterations; 2 barriers per 400 KB instead of per 100 KB; 4x fewer
// same-address global atomics. launch_bounds(320,5) caps VGPR at 102 so
// 4 blocks/CU (20 waves) fit without spilling (R3 lesson: (320,8) spilled).

#define BATCH 32
#define HH 1280
#define WW 1280
#define PH 128
#define PW 128
#define SC 10
#define NT 320                      // threads per block (5 waves)
#define KD 10                       // float4-pair iterations per band per thread
#define BPB 4                       // bands per block
#define NITER (KD * BPB)            // 40 pipelined iterations
#define PD 5                        // software-pipeline depth (10 loads in flight)

static constexpr float EPSV = 1e-20f;
static constexpr float LN2  = 0.6931471805599453f;
static constexpr float INV_NB = 1.0f / (float)(BATCH * HH * WW);   // bce mean
static constexpr float INV_NM = 1.0f / (float)(BATCH * PH * PW);   // mse mean

__global__ __launch_bounds__(NT, 5) void srloss_kernel(
    const float* __restrict__ output,
    const float* __restrict__ target,
    const float* __restrict__ inp,
    float* __restrict__ out)
{
    __shared__ float psum[BPB * PW];   // pooled column sums, 4 bands
    __shared__ float red[NT / 64];     // cross-wave reduction scratch

    const int t = threadIdx.x;
    const int band0 = blockIdx.x * BPB;   // first band of this block
    const int b   = band0 >> 7;           // band0 / 128 (BPB divides 128 -> same b)
    const int pr0 = band0 & 127;          // band0 % 128

    #pragma unroll
    for (int e = t; e < BPB * PW; e += NT) psum[e] = 0.0f;
    __syncthreads();                   // before any loads issue (no vmcnt drain)

    const size_t base = ((size_t)b * HH + (size_t)pr0 * SC) * WW;
    const float4* __restrict__ o4p = (const float4*)(output + base) + t;
    const float4* __restrict__ t4p = (const float4*)(target + base) + t;

    // iter n -> band i = n/KD, row k = n%KD; float4 offset (compile-time after unroll)
    // off(n) = i*(SC*WW/4) + k*(WW/4) = (n/10)*3200 + (n%10)*320
    float4 ob[PD], tb[PD];
    #pragma unroll
    for (int n = 0; n < PD; ++n) {
        const int off = (n / KD) * (SC * WW / 4) + (n % KD) * (WW / 4);
        ob[n] = o4p[off];
        tb[n] = t4p[off];
    }

    // c = 4t is band- and row-invariant -> pooled-column mapping computed once
    const int col0 = 4 * t;
    const int p0 = col0 / SC;
    const bool straddle = (col0 % SC) == 8;  // o[2],o[3] belong to p0+1

    float acc2 = 0.0f;              // sum log2(oc)
    float accd = 0.0f;              // sum t*(log2(om)-log2(oc))
    float s0 = 0.0f, s1 = 0.0f;     // pooled sums: halves of the float4

    #pragma unroll
    for (int n = 0; n < NITER; ++n) {
        const float4 o4 = ob[n % PD];
        const float4 t4 = tb[n % PD];
        if (n + PD < NITER) {       // compile-time after unroll
            const int m = n + PD;
            const int off = (m / KD) * (SC * WW / 4) + (m % KD) * (WW / 4);
            ob[n % PD] = o4p[off];
            tb[n % PD] = t4p[off];
        }
        const float o[4]  = {o4.x, o4.y, o4.z, o4.w};
        const float tg[4] = {t4.x, t4.y, t4.z, t4.w};
        #pragma unroll
        for (int j = 0; j < 4; ++j) {
            const float om = fmaxf(o[j], EPSV);
            const float oc = fmaxf(1.0f - o[j], EPSV);
            const float l1 = __log2f(om);
            const float l2 = __log2f(oc);
            acc2 += l2;
            accd += tg[j] * (l1 - l2);
        }
        s0 += o[0] + o[1];
        s1 += o[2] + o[3];

        if ((n % KD) == KD - 1) {   // end of band i: commit pooled sums
            const int i = n / KD;
            if (straddle) {
                atomicAdd(&psum[i * PW + p0],     s0);
                atomicAdd(&psum[i * PW + p0 + 1], s1);
            } else {
                atomicAdd(&psum[i * PW + p0], s0 + s1);
            }
            s0 = 0.0f;
            s1 = 0.0f;
        }
    }
    const float bce_acc = LN2 * (acc2 + accd);
    __syncthreads();

    // MSE terms: 512 pooled elements over 320 threads (t, t+320 for t<192)
    float mse_acc = 0.0f;
    #pragma unroll
    for (int e = t; e < BPB * PW; e += NT) {
        const float pooled = psum[e] * (1.0f / (float)(SC * SC));
        const int i = e >> 7;               // e / PW
        const int c = e & (PW - 1);         // e % PW
        const float iv = inp[(size_t)(band0 + i) * PW + c];
        const float d = iv - pooled;
        mse_acc += d * d;
    }

    // per-block contribution, pre-normalized
    float contrib = (-INV_NB) * bce_acc + INV_NM * mse_acc;

    #pragma unroll
    for (int off = 32; off > 0; off >>= 1)
        contrib += __shfl_down(contrib, off, 64);
    if ((t & 63) == 0) red[t >> 6] = contrib;
    __syncthreads();
    if (t == 0) {
        float s = 0.0f;
        #pragma unroll
        for (int w = 0; w < NT / 64; ++w) s += red[w];
        atomicAdd(out, s);
    }
}

extern "C" void kernel_launch(void* const* d_in, const int* in_sizes, int n_in,
                              void* d_out, int out_size, void* d_ws, size_t ws_size,
                              hipStream_t stream) {
    const float* output = (const float*)d_in[0];
    const float* target = (const float*)d_in[1];
    const float* inp    = (const float*)d_in[2];
    float* out = (float*)d_out;

    // d_out is poisoned (0xAA) before every timed replay; zero it ourselves.
    hipMemsetAsync(out, 0, sizeof(float), stream);

    srloss_kernel<<<(BATCH * PH) / BPB, NT, 0, stream>>>(output, target, inp, out);
}

// Round 2
// 605.451 us; speedup vs baseline: 2.0532x; 2.0532x over previous
//
#include <hip/hip_runtime.h>

// SRLoss: loss = mean((inp - avgpool10x10(output))^2) + BCE(output, target)
// output/target: [32,1,1280,1280] f32; inp: [32,1,128,128] f32; out: scalar f32.
//
// R5 post-mortem: band-batching with __launch_bounds__(320,5) + 40-deep unroll
// spilled (WRITE 128B -> 1.34MB, FETCH 206 -> 884MB, 973us). Reverted to the
// exact R4 body (44 VGPR, no spill, 138us).
// R6: theory = the 4096 same-address atomicAdd(out, s) chain serializes at the
// device coherence point (~30ns each ~ 123us ~ measured 138us) and IS the
// critical path (streaming work only needs ~60-70us). Replace with per-block
// partials in d_ws + counter + last-block reduction (rocPRIM-style). Final sum
// is now deterministic as a bonus.

#define BATCH 32
#define HH 1280
#define WW 1280
#define PH 128
#define PW 128
#define SC 10
#define NT 320                      // threads per block (5 waves)
#define KD 10                       // float4-pair iterations per thread
#define PD 5                       // software-pipeline depth (full preload)
#define NB (BATCH * PH)            // 4096 blocks

static constexpr float EPSV = 1e-20f;
static constexpr float LN2  = 0.6931471805599453f;
static constexpr float INV_NBCE = 1.0f / (float)(BATCH * HH * WW);   // bce mean
static constexpr float INV_NM   = 1.0f / (float)(BATCH * PH * PW);   // mse mean

__global__ __launch_bounds__(NT, 4) void srloss_kernel(
    const float* __restrict__ output,
    const float* __restrict__ target,
    const float* __restrict__ inp,
    float* __restrict__ partials,
    unsigned int* __restrict__ counter,
    float* __restrict__ out)
{
    __shared__ float psum[PW];      // pooled column sums for this band
    __shared__ float red[NT / 64];  // cross-wave reduction scratch
    __shared__ int is_last;

    const int t = threadIdx.x;
    const int band = blockIdx.x;    // 0 .. BATCH*PH-1
    const int b = band >> 7;        // band / 128
    const int pr = band & 127;      // band % 128

    if (t < PW) psum[t] = 0.0f;
    __syncthreads();                // before any loads issue (no vmcnt drain)

    const size_t base = ((size_t)b * HH + (size_t)pr * SC) * WW;
    const float4* __restrict__ o4p = (const float4*)(output + base) + t;
    const float4* __restrict__ t4p = (const float4*)(target + base) + t;

    // depth-5 rotating pipeline: up to 10 outstanding 16B loads per lane
    float4 ob[PD], tb[PD];
    #pragma unroll
    for (int k = 0; k < PD; ++k) {
        ob[k] = o4p[NT * k];
        tb[k] = t4p[NT * k];
    }

    float acc2 = 0.0f;              // sum log2(oc)
    float accd = 0.0f;              // sum t*(log2(om)-log2(oc))
    float s0 = 0.0f, s1 = 0.0f;     // pooled sums: halves of the float4
    #pragma unroll
    for (int k = 0; k < KD; ++k) {
        const float4 o4 = ob[k % PD];
        const float4 t4 = tb[k % PD];
        if (k + PD < KD) {          // compile-time after unroll
            ob[k % PD] = o4p[NT * (k + PD)];
            tb[k % PD] = t4p[NT * (k + PD)];
        }
        const float o[4]  = {o4.x, o4.y, o4.z, o4.w};
        const float tg[4] = {t4.x, t4.y, t4.z, t4.w};
        #pragma unroll
        for (int j = 0; j < 4; ++j) {
            const float om = fmaxf(o[j], EPSV);
            const float oc = fmaxf(1.0f - o[j], EPSV);
            const float l1 = __log2f(om);
            const float l2 = __log2f(oc);
            acc2 += l2;
            accd += tg[j] * (l1 - l2);
        }
        s0 += o[0] + o[1];
        s1 += o[2] + o[3];
    }
    const float bce_acc = LN2 * (acc2 + accd);

    // c = t + 320k -> row = k, col0 = 4t for all k (k-invariant mapping)
    const int col0 = 4 * t;
    const int p0 = col0 / SC;
    if ((col0 % SC) == 8) {         // straddle: o[2],o[3] belong to p0+1
        atomicAdd(&psum[p0],     s0);
        atomicAdd(&psum[p0 + 1], s1);
    } else {
        atomicAdd(&psum[p0], s0 + s1);
    }
    __syncthreads();

    // MSE terms: one pooled element per thread for t < 128
    float mse_acc = 0.0f;
    if (t < PW) {
        const float pooled = psum[t] * (1.0f / (float)(SC * SC));
        const float iv = inp[(size_t)band * PW + t];
        const float d = iv - pooled;
        mse_acc = d * d;
    }

    // per-block contribution, pre-normalized
    float contrib = (-INV_NBCE) * bce_acc + INV_NM * mse_acc;

    #pragma unroll
    for (int off = 32; off > 0; off >>= 1)
        contrib += __shfl_down(contrib, off, 64);
    if ((t & 63) == 0) red[t >> 6] = contrib;
    __syncthreads();

    // publish per-block partial to a DISTINCT slot (no same-address FP chain)
    if (t == 0) {
        float s = 0.0f;
        #pragma unroll
        for (int w = 0; w < NT / 64; ++w) s += red[w];
        partials[band] = s;
        __threadfence();                         // release partial
        const unsigned int old = atomicAdd(counter, 1u);
        is_last = (old == (unsigned int)(NB - 1)) ? 1 : 0;
    }
    __syncthreads();

    // last-arriving block reduces all partials and writes the scalar
    if (is_last) {
        __threadfence();                         // acquire side
        float s2 = 0.0f;
        for (int e = t; e < NB; e += NT) s2 += partials[e];
        #pragma unroll
        for (int off = 32; off > 0; off >>= 1)
            s2 += __shfl_down(s2, off, 64);
        if ((t & 63) == 0) red[t >> 6] = s2;
        __syncthreads();
        if (t == 0) {
            float tot = 0.0f;
            #pragma unroll
            for (int w = 0; w < NT / 64; ++w) tot += red[w];
            out[0] = tot;
        }
    }
}

extern "C" void kernel_launch(void* const* d_in, const int* in_sizes, int n_in,
                              void* d_out, int out_size, void* d_ws, size_t ws_size,
                              hipStream_t stream) {
    const float* output = (const float*)d_in[0];
    const float* target = (const float*)d_in[1];
    const float* inp    = (const float*)d_in[2];
    float* out = (float*)d_out;

    // d_ws layout: [0..255] counter region (zeroed each launch), then partials.
    unsigned int* counter = (unsigned int*)d_ws;
    float* partials = (float*)((char*)d_ws + 256);

    hipMemsetAsync(d_ws, 0, 256, stream);        // reset counter (graph-safe)

    srloss_kernel<<<NB, NT, 0, stream>>>(output, target, inp,
                                         partials, counter, out);
}

// Round 3
// 406.446 us; speedup vs baseline: 3.0585x; 1.4896x over previous
//
#include <hip/hip_runtime.h>

// SRLoss: loss = mean((inp - avgpool10x10(output))^2) + BCE(output, target)
// output/target: [32,1,1280,1280] f32; inp: [32,1,128,128] f32; out: scalar f32.
//
// R6 post-mortem: partials + counter + __threadfence() regressed 138 -> 330us.
// The device-scope fence (L2 writeback, 4096x) trashed the memory path:
// BW fell 3.05 -> 1.28 TB/s at identical FETCH_SIZE. Fences are poison here.
// R7: clean A/B on the atomic theory. Kernel 1 = exact R4 streaming body
// (44 VGPR, no spill) ending in a PLAIN STORE of the block partial to d_ws
// (no atomic, no fence). Kernel 2 = one 512-thread block reducing the 4096
// partials -> out[0]. Kernel boundary gives cross-XCD visibility.
// If R4 was atomic-drain-bound: k1 ~70-95us. If not: k1 ~135us and the
// limiter is latency/residency, not the reduction.

#define BATCH 32
#define HH 1280
#define WW 1280
#define PH 128
#define PW 128
#define SC 10
#define NT 320                      // threads per block (5 waves)
#define KD 10                       // float4-pair iterations per thread
#define PD 5                        // software-pipeline depth (full preload)
#define NB (BATCH * PH)             // 4096 blocks
#define NT2 512                     // reduce-kernel threads

static constexpr float EPSV = 1e-20f;
static constexpr float LN2  = 0.6931471805599453f;
static constexpr float INV_NBCE = 1.0f / (float)(BATCH * HH * WW);   // bce mean
static constexpr float INV_NM   = 1.0f / (float)(BATCH * PH * PW);   // mse mean

__global__ __launch_bounds__(NT, 4) void srloss_partial(
    const float* __restrict__ output,
    const float* __restrict__ target,
    const float* __restrict__ inp,
    float* __restrict__ partials)
{
    __shared__ float psum[PW];      // pooled column sums for this band
    __shared__ float red[NT / 64];  // cross-wave reduction scratch

    const int t = threadIdx.x;
    const int band = blockIdx.x;    // 0 .. BATCH*PH-1
    const int b = band >> 7;        // band / 128
    const int pr = band & 127;      // band % 128

    if (t < PW) psum[t] = 0.0f;
    __syncthreads();                // before any loads issue (no vmcnt drain)

    const size_t base = ((size_t)b * HH + (size_t)pr * SC) * WW;
    const float4* __restrict__ o4p = (const float4*)(output + base) + t;
    const float4* __restrict__ t4p = (const float4*)(target + base) + t;

    // depth-5 rotating pipeline: up to 10 outstanding 16B loads per lane
    float4 ob[PD], tb[PD];
    #pragma unroll
    for (int k = 0; k < PD; ++k) {
        ob[k] = o4p[NT * k];
        tb[k] = t4p[NT * k];
    }

    float acc2 = 0.0f;              // sum log2(oc)
    float accd = 0.0f;              // sum t*(log2(om)-log2(oc))
    float s0 = 0.0f, s1 = 0.0f;     // pooled sums: halves of the float4
    #pragma unroll
    for (int k = 0; k < KD; ++k) {
        const float4 o4 = ob[k % PD];
        const float4 t4 = tb[k % PD];
        if (k + PD < KD) {          // compile-time after unroll
            ob[k % PD] = o4p[NT * (k + PD)];
            tb[k % PD] = t4p[NT * (k + PD)];
        }
        const float o[4]  = {o4.x, o4.y, o4.z, o4.w};
        const float tg[4] = {t4.x, t4.y, t4.z, t4.w};
        #pragma unroll
        for (int j = 0; j < 4; ++j) {
            const float om = fmaxf(o[j], EPSV);
            const float oc = fmaxf(1.0f - o[j], EPSV);
            const float l1 = __log2f(om);
            const float l2 = __log2f(oc);
            acc2 += l2;
            accd += tg[j] * (l1 - l2);
        }
        s0 += o[0] + o[1];
        s1 += o[2] + o[3];
    }
    const float bce_acc = LN2 * (acc2 + accd);

    // c = t + 320k -> row = k, col0 = 4t for all k (k-invariant mapping)
    const int col0 = 4 * t;
    const int p0 = col0 / SC;
    if ((col0 % SC) == 8) {         // straddle: o[2],o[3] belong to p0+1
        atomicAdd(&psum[p0],     s0);
        atomicAdd(&psum[p0 + 1], s1);
    } else {
        atomicAdd(&psum[p0], s0 + s1);
    }
    __syncthreads();

    // MSE terms: one pooled element per thread for t < 128
    float mse_acc = 0.0f;
    if (t < PW) {
        const float pooled = psum[t] * (1.0f / (float)(SC * SC));
        const float iv = inp[(size_t)band * PW + t];
        const float d = iv - pooled;
        mse_acc = d * d;
    }

    // per-block contribution, pre-normalized
    float contrib = (-INV_NBCE) * bce_acc + INV_NM * mse_acc;

    #pragma unroll
    for (int off = 32; off > 0; off >>= 1)
        contrib += __shfl_down(contrib, off, 64);
    if ((t & 63) == 0) red[t >> 6] = contrib;
    __syncthreads();

    // plain store to a distinct slot: no RMW chain, no fence
    if (t == 0) {
        float s = 0.0f;
        #pragma unroll
        for (int w = 0; w < NT / 64; ++w) s += red[w];
        partials[band] = s;
    }
}

__global__ __launch_bounds__(NT2) void srloss_reduce(
    const float* __restrict__ partials,
    float* __restrict__ out)
{
    __shared__ float red[NT2 / 64];
    const int t = threadIdx.x;

    // 4096 floats = 1024 float4; 512 threads x 2 float4 each
    const float4 v0 = ((const float4*)partials)[t];
    const float4 v1 = ((const float4*)partials)[t + NT2];
    float s = (v0.x + v0.y) + (v0.z + v0.w) + (v1.x + v1.y) + (v1.z + v1.w);

    #pragma unroll
    for (int off = 32; off > 0; off >>= 1)
        s += __shfl_down(s, off, 64);
    if ((t & 63) == 0) red[t >> 6] = s;
    __syncthreads();
    if (t == 0) {
        float tot = 0.0f;
        #pragma unroll
        for (int w = 0; w < NT2 / 64; ++w) tot += red[w];
        out[0] = tot;
    }
}

extern "C" void kernel_launch(void* const* d_in, const int* in_sizes, int n_in,
                              void* d_out, int out_size, void* d_ws, size_t ws_size,
                              hipStream_t stream) {
    const float* output = (const float*)d_in[0];
    const float* target = (const float*)d_in[1];
    const float* inp    = (const float*)d_in[2];
    float* out = (float*)d_out;
    float* partials = (float*)d_ws;              // 4096 floats = 16 KB

    srloss_partial<<<NB, NT, 0, stream>>>(output, target, inp, partials);
    srloss_reduce<<<1, NT2, 0, stream>>>(partials, out);
}